// Round 8
// baseline (316.166 us; speedup 1.0000x reference)
//
#include <hip/hip_runtime.h>

typedef __attribute__((ext_vector_type(8))) short bf16x8_t;
typedef __attribute__((ext_vector_type(4))) float f32x4_t;

#define BATCH 4
#define CH 64
#define HIN 256
#define WIN 512
#define NDISP 65
#define TY 2
#define TX 254
#define NSTEP 8

// LDS: single-buffer bf16 staging + 17-diagonal Q chunk + aux  (63.6 KB -> 2 blocks/CU)
#define X0_OFF 0
#define X0_PS 8192               // 128 pos-lines x 64B per parity
#define X1_OFF 16384
#define X1_PS 12288              // 192 pos-lines x 64B per parity
#define QB_OFF 40960             // float[17][257] = 17476 B
#define S0X_OFF 58448
#define L0X_OFF 59472
#define S1X_OFF 60496
#define L1X_OFF 62032
#define SMEM_BYTES 63568

// workspace float offsets (stats pre-passes)
#define CS0_OFF 0
#define CQ0_OFF  524288
#define CS1_OFF 1048576
#define CQ1_OFF 1572864
#define SB0_OFF 2097152
#define LB0_OFF 2621440
#define SB1_OFF 3145728          // [B][H][648], i = v+66
#define LB1_OFF 3809280

// ---------------- pass A: per-(b,y) channel column sums ----------------
__global__ __launch_bounds__(512)
void colsum_kernel(const float* __restrict__ x0, const float* __restrict__ x1,
                   float* __restrict__ ws) {
  const int y = blockIdx.x, b = blockIdx.y, x = threadIdx.x;
  const size_t plane = (size_t)HIN * WIN;
  const float* p0 = x0 + (size_t)b * CH * plane + (size_t)y * WIN + x;
  const float* p1 = x1 + (size_t)b * CH * plane + (size_t)y * WIN + x;
  float s0 = 0.f, q0 = 0.f, s1 = 0.f, q1 = 0.f;
#pragma unroll 8
  for (int c = 0; c < CH; ++c) {
    const float v = p0[c * plane];
    const float w = p1[c * plane];
    s0 += v; q0 += v * v;
    s1 += w; q1 += w * w;
  }
  const size_t o = ((size_t)b * HIN + y) * WIN + x;
  ws[CS0_OFF + o] = s0; ws[CQ0_OFF + o] = q0;
  ws[CS1_OFF + o] = s1; ws[CQ1_OFF + o] = q1;
}

// ---------------- pass B: 3x3 boxed patch stats + norms ----------------
__global__ __launch_bounds__(512)
void boxnorm_kernel(float* __restrict__ ws) {
  const int y = blockIdx.x, b = blockIdx.y;
  const int tid = threadIdx.x;
  const float invn = 1.f / 576.f;
  const int ylo = (y > 0) ? y - 1 : 0;
  const int yhi = (y < HIN - 1) ? y + 1 : HIN - 1;
  {
    const int x = tid;
    float s = 0.f, q = 0.f;
    for (int yy = ylo; yy <= yhi; ++yy) {
      const float* rs = ws + CS0_OFF + ((size_t)b * HIN + yy) * WIN;
      const float* rq = ws + CQ0_OFF + ((size_t)b * HIN + yy) * WIN;
      const int xlo = (x > 0) ? x - 1 : 0;
      const int xhi = (x < WIN - 1) ? x + 1 : WIN - 1;
      for (int xx = xlo; xx <= xhi; ++xx) { s += rs[xx]; q += rq[xx]; }
    }
    const size_t o = ((size_t)b * HIN + y) * WIN + x;
    ws[SB0_OFF + o] = s;
    ws[LB0_OFF + o] = sqrtf(fmaxf(q - s * s * invn, 0.f));
  }
  for (int i = tid; i < 648; i += 512) {
    const int v = i - 66;
    float s = 0.f, q = 0.f;
    const int xlo = (v - 1 > 0) ? v - 1 : 0;
    const int xhi = (v + 1 < WIN - 1) ? v + 1 : WIN - 1;
    if (v + 1 >= 0 && v - 1 < WIN) {
      for (int yy = ylo; yy <= yhi; ++yy) {
        const float* rs = ws + CS1_OFF + ((size_t)b * HIN + yy) * WIN;
        const float* rq = ws + CQ1_OFF + ((size_t)b * HIN + yy) * WIN;
        for (int xx = xlo; xx <= xhi; ++xx) { s += rs[xx]; q += rq[xx]; }
      }
    }
    const size_t o = ((size_t)b * HIN + y) * 648 + i;
    ws[SB1_OFF + o] = s;
    ws[LB1_OFF + o] = sqrtf(fmaxf(q - s * s * invn, 0.f));
  }
}

// ---------------- main: pipelined banded MFMA cost volume + epilogue ----------------
__global__ __launch_bounds__(512, 2)
void corrzn_kernel(const float* __restrict__ x0, const float* __restrict__ x1,
                   const float* __restrict__ ws, float* __restrict__ out) {
  __shared__ __align__(16) char smem[SMEM_BYTES];

  const int tid  = threadIdx.x;
  const int lane = tid & 63;
  const int wv   = tid >> 6;
  const int p    = wv & 1;
  const int chunk0 = 2 * (wv >> 1);
  const int lm = lane & 15;
  const int lk = lane >> 4;
  const int t5  = tid & 31;       // x-pair lane within cp group
  const int cpx = tid >> 5;       // channel-pair 0..15

  const int x0blk = blockIdx.x * TX;
  const int y0    = blockIdx.y * TY;
  const int b     = blockIdx.z;

  const size_t plane = (size_t)HIN * WIN;
  const float* x0b = x0 + (size_t)b * CH * plane;
  const float* x1b = x1 + (size_t)b * CH * plane;

  f32x4_t acc[TY][2][5];
#pragma unroll
  for (int t = 0; t < TY; ++t)
#pragma unroll
    for (int mc = 0; mc < 2; ++mc)
#pragma unroll
      for (int T = 0; T < 5; ++T)
        acc[t][mc][T] = (f32x4_t){0.f, 0.f, 0.f, 0.f};

  float2 R0[12], R1[12];          // prefetched (ch even, ch odd) x-pairs

  // issue step-k global loads into registers (coalesced aligned float2)
  auto prefetch = [&](int k) {
    const int r = k >> 1, cc = k & 1;
    const int orow = y0 + r - 1;
    const bool rowok = (orow >= 0) && (orow < HIN);
    const int ro = rowok ? orow : 0;
    const float* s0p = x0b + (size_t)(cc * 32 + 2 * cpx) * plane + (size_t)ro * WIN;
    const float* s1p = x1b + (size_t)(cc * 32 + 2 * cpx) * plane + (size_t)ro * WIN;
#pragma unroll
    for (int it = 0; it < 5; ++it) {       // x0: wp 0..128
      const int wp = 32 * it + t5;
      const int xg = x0blk - 2 + 2 * wp;
      float2 a = {0.f, 0.f}, c = {0.f, 0.f};
      if (rowok && wp <= 128 && xg >= 0 && xg < WIN - 1) {
        a = *(const float2*)(s0p + xg);
        c = *(const float2*)(s0p + plane + xg);
      }
      R0[it] = a; R1[it] = c;
    }
#pragma unroll
    for (int it = 0; it < 7; ++it) {       // x1: wp 0..192
      const int wp = 32 * it + t5;
      const int xg = x0blk - 66 + 2 * wp;
      float2 a = {0.f, 0.f}, c = {0.f, 0.f};
      if (rowok && wp <= 192 && xg >= 0 && xg < WIN - 1) {
        a = *(const float2*)(s1p + xg);
        c = *(const float2*)(s1p + plane + xg);
      }
      R0[5 + it] = a; R1[5 + it] = c;
    }
  };

  // write prefetched registers to swizzled bf16 LDS
  auto wstage = [&]() {
#pragma unroll
    for (int it = 0; it < 12; ++it) {
      const bool isx1 = it >= 5;
      const int wp = 32 * (isx1 ? it - 5 : it) + t5;
      const int base = isx1 ? X1_OFF : X0_OFF;
      const int ps   = isx1 ? X1_PS : X0_PS;
      const int pmax = isx1 ? 192 : 128;
      unsigned pkA, pkB;
      asm("v_cvt_pk_bf16_f32 %0, %1, %2" : "=v"(pkA) : "v"(R0[it].x), "v"(R1[it].x));
      asm("v_cvt_pk_bf16_f32 %0, %1, %2" : "=v"(pkB) : "v"(R0[it].y), "v"(R1[it].y));
      if (wp >= 1 && wp <= pmax) {         // parity 1, pos wp-1
        const int pos = wp - 1;
        const int slot = (cpx >> 2) ^ ((pos >> 1) & 3);
        *(unsigned*)(smem + base + ps + pos * 64 + slot * 16 + (cpx & 3) * 4) = pkA;
      }
      if (wp <= pmax - 1) {                // parity 0, pos wp
        const int pos = wp;
        const int slot = (cpx >> 2) ^ ((pos >> 1) & 3);
        *(unsigned*)(smem + base + pos * 64 + slot * 16 + (cpx & 3) * 4) = pkB;
      }
    }
  };

  prefetch(0);

  // ============ K-loop: 4 padded rows x 2 channel chunks ============
#pragma unroll
  for (int k = 0; k < NSTEP; ++k) {
    const int r = k >> 1;

    if (k) __builtin_amdgcn_s_barrier();   // previous step's frag reads issued
    asm volatile("" ::: "memory");
    wstage();                              // consumes R(k) (vmcnt waits)
    if (k + 1 < NSTEP) prefetch(k + 1);    // next loads fly over this step
    asm volatile("s_waitcnt lgkmcnt(0)" ::: "memory");
    __builtin_amdgcn_s_barrier();
    asm volatile("" ::: "memory");

    bf16x8_t afr[2], bfr[6];
#pragma unroll
    for (int mc = 0; mc < 2; ++mc) {
      const int pos = 16 * (chunk0 + mc) + lm;
      const int slot = lk ^ ((pos >> 1) & 3);
      afr[mc] = *(const bf16x8_t*)(smem + X0_OFF + p * X0_PS + pos * 64 + slot * 16);
    }
#pragma unroll
    for (int u = 0; u < 6; ++u) {
      const int pos = 16 * (chunk0 + u) + lm;
      const int slot = lk ^ ((pos >> 1) & 3);
      bfr[u] = *(const bf16x8_t*)(smem + X1_OFF + p * X1_PS + pos * 64 + slot * 16);
    }
#pragma unroll
    for (int t = 0; t < TY; ++t) {
      if (t >= r - 2 && t <= r) {
#pragma unroll
        for (int mc = 0; mc < 2; ++mc)
#pragma unroll
          for (int T = 0; T < 5; ++T)
            acc[t][mc][T] = __builtin_amdgcn_mfma_f32_16x16x32_bf16(
                afr[mc], bfr[mc + T], acc[t][mc][T], 0, 0, 0);
      }
    }
  }

  // ============ epilogue: per row, 4 di-chunks of 17 ============
  float* Qc  = (float*)(smem + QB_OFF);
  float* s0x = (float*)(smem + S0X_OFF);
  float* l0x = (float*)(smem + L0X_OFF);
  float* s1x = (float*)(smem + S1X_OFF);
  float* l1x = (float*)(smem + L1X_OFF);
  const float invn = 1.f / 576.f;

#pragma unroll
  for (int t = 0; t < TY; ++t) {
    const int row = y0 + t;
    __syncthreads();                       // staging/Q readers done
    for (int i = tid; i < 254; i += 512) {
      const int x = x0blk + i;
      const size_t o = ((size_t)b * HIN + row) * WIN + x;
      s0x[i] = (x < WIN) ? ws[SB0_OFF + o] : 0.f;
      l0x[i] = (x < WIN) ? ws[LB0_OFF + o] : 0.f;
    }
    for (int j2 = tid; j2 < 382; j2 += 512) {
      const int idx = x0blk + 2 + j2;
      const size_t o = ((size_t)b * HIN + row) * 648 + idx;
      s1x[j2] = (idx < 648) ? ws[SB1_OFF + o] : 0.f;
      l1x[j2] = (idx < 648) ? ws[LB1_OFF + o] : 0.f;
    }
    for (int c = 0; c < 4; ++c) {
      const int c0 = 17 * c;
      const int nd = (c == 3) ? 14 : 17;
      __syncthreads();
#pragma unroll
      for (int mc = 0; mc < 2; ++mc) {
#pragma unroll
        for (int T = 0; T < 5; ++T) {
#pragma unroll
          for (int q = 0; q < 4; ++q) {
            const int mg = 16 * (chunk0 + mc) + lk * 4 + q;
            const int di = 16 * T + lm - 4 * lk - q;
            if (di >= c0 && di < c0 + nd)
              Qc[(di - c0) * 257 + 2 * mg + p] = acc[t][mc][T][q];
          }
        }
      }
      __syncthreads();
      const int tot = nd * TX;
      for (int oi = tid; oi < tot; oi += 512) {
        const int dic = oi / TX;
        const int xl = oi - dic * TX;
        const int x = x0blk + xl;
        if (x < WIN) {
          const int di = c0 + dic;
          const float q3 = Qc[dic * 257 + xl] + Qc[dic * 257 + xl + 1] + Qc[dic * 257 + xl + 2];
          const int j = xl + 2 * di;
          const float numer = q3 - s0x[xl] * s1x[j] * invn;
          const float den = l0x[xl] * l1x[j] + 1e-8f;
          float rd;
          asm("v_rcp_f32 %0, %1" : "=v"(rd) : "v"(den));
          out[(((size_t)b * NDISP + di) * HIN + row) * WIN + x] = numer * rd;
        }
      }
    }
  }
}

extern "C" void kernel_launch(void* const* d_in, const int* in_sizes, int n_in,
                              void* d_out, int out_size, void* d_ws, size_t ws_size,
                              hipStream_t stream) {
  const float* x0 = (const float*)d_in[0];
  const float* x1 = (const float*)d_in[1];
  float* out = (float*)d_out;
  float* wsf = (float*)d_ws;

  colsum_kernel<<<dim3(HIN, BATCH), 512, 0, stream>>>(x0, x1, wsf);
  boxnorm_kernel<<<dim3(HIN, BATCH), 512, 0, stream>>>(wsf);
  corrzn_kernel<<<dim3(3, HIN / TY, BATCH), 512, 0, stream>>>(x0, x1, wsf, out);
}

// Round 9
// 263.387 us; speedup vs baseline: 1.2004x; 1.2004x over previous
//
#include <hip/hip_runtime.h>

typedef __attribute__((ext_vector_type(8))) short bf16x8_t;
typedef __attribute__((ext_vector_type(4))) float f32x4_t;

#define BATCH 4
#define CH 64
#define HIN 256
#define WIN 512
#define NDISP 65
#define TY 2
#define TX 254
#define NSTEP 8

// LDS: double-buffered bf16 staging; epilogue Q/aux UNIONED onto it (dead after K-loop)
#define BUF_BYTES 40960
#define X0_OFF 0
#define X0_PS 8192               // 128 pos-lines x 64B per parity
#define X1_OFF 16384
#define X1_PS 12288              // 192 pos-lines x 64B per parity
#define QB_OFF 0                 // float[65][257] = 66820 B (aliases staging)
#define S0X_OFF 66824
#define L0X_OFF 67848
#define S1X_OFF 68872
#define L1X_OFF 70408
#define SMEM_BYTES 81920         // exactly 80 KB -> 2 blocks/CU

// workspace float offsets (stats pre-passes)
#define CS0_OFF 0
#define CQ0_OFF  524288
#define CS1_OFF 1048576
#define CQ1_OFF 1572864
#define SB0_OFF 2097152
#define LB0_OFF 2621440
#define SB1_OFF 3145728          // [B][H][648], i = v+66
#define LB1_OFF 3809280

// ---------------- pass A: per-(b,y) channel column sums ----------------
__global__ __launch_bounds__(512)
void colsum_kernel(const float* __restrict__ x0, const float* __restrict__ x1,
                   float* __restrict__ ws) {
  const int y = blockIdx.x, b = blockIdx.y, x = threadIdx.x;
  const size_t plane = (size_t)HIN * WIN;
  const float* p0 = x0 + (size_t)b * CH * plane + (size_t)y * WIN + x;
  const float* p1 = x1 + (size_t)b * CH * plane + (size_t)y * WIN + x;
  float s0 = 0.f, q0 = 0.f, s1 = 0.f, q1 = 0.f;
#pragma unroll 8
  for (int c = 0; c < CH; ++c) {
    const float v = p0[c * plane];
    const float w = p1[c * plane];
    s0 += v; q0 += v * v;
    s1 += w; q1 += w * w;
  }
  const size_t o = ((size_t)b * HIN + y) * WIN + x;
  ws[CS0_OFF + o] = s0; ws[CQ0_OFF + o] = q0;
  ws[CS1_OFF + o] = s1; ws[CQ1_OFF + o] = q1;
}

// ---------------- pass B: 3x3 boxed patch stats + norms ----------------
__global__ __launch_bounds__(512)
void boxnorm_kernel(float* __restrict__ ws) {
  const int y = blockIdx.x, b = blockIdx.y;
  const int tid = threadIdx.x;
  const float invn = 1.f / 576.f;
  const int ylo = (y > 0) ? y - 1 : 0;
  const int yhi = (y < HIN - 1) ? y + 1 : HIN - 1;
  {
    const int x = tid;
    float s = 0.f, q = 0.f;
    for (int yy = ylo; yy <= yhi; ++yy) {
      const float* rs = ws + CS0_OFF + ((size_t)b * HIN + yy) * WIN;
      const float* rq = ws + CQ0_OFF + ((size_t)b * HIN + yy) * WIN;
      const int xlo = (x > 0) ? x - 1 : 0;
      const int xhi = (x < WIN - 1) ? x + 1 : WIN - 1;
      for (int xx = xlo; xx <= xhi; ++xx) { s += rs[xx]; q += rq[xx]; }
    }
    const size_t o = ((size_t)b * HIN + y) * WIN + x;
    ws[SB0_OFF + o] = s;
    ws[LB0_OFF + o] = sqrtf(fmaxf(q - s * s * invn, 0.f));
  }
  for (int i = tid; i < 648; i += 512) {
    const int v = i - 66;
    float s = 0.f, q = 0.f;
    const int xlo = (v - 1 > 0) ? v - 1 : 0;
    const int xhi = (v + 1 < WIN - 1) ? v + 1 : WIN - 1;
    if (v + 1 >= 0 && v - 1 < WIN) {
      for (int yy = ylo; yy <= yhi; ++yy) {
        const float* rs = ws + CS1_OFF + ((size_t)b * HIN + yy) * WIN;
        const float* rq = ws + CQ1_OFF + ((size_t)b * HIN + yy) * WIN;
        for (int xx = xlo; xx <= xhi; ++xx) { s += rs[xx]; q += rq[xx]; }
      }
    }
    const size_t o = ((size_t)b * HIN + y) * 648 + i;
    ws[SB1_OFF + o] = s;
    ws[LB1_OFF + o] = sqrtf(fmaxf(q - s * s * invn, 0.f));
  }
}

// ---------------- main: pipelined banded MFMA cost volume + epilogue ----------------
__global__ __launch_bounds__(512, 2)
void corrzn_kernel(const float* __restrict__ x0, const float* __restrict__ x1,
                   const float* __restrict__ ws, float* __restrict__ out) {
  __shared__ __align__(16) char smem[SMEM_BYTES];

  const int tid  = threadIdx.x;
  const int lane = tid & 63;
  const int wv   = tid >> 6;
  const int p    = wv & 1;
  const int chunk0 = 2 * (wv >> 1);
  const int lm = lane & 15;
  const int lk = lane >> 4;
  const int t5  = tid & 31;       // x-pair lane within cp group
  const int cpx = tid >> 5;       // channel-pair 0..15

  const int x0blk = blockIdx.x * TX;
  const int y0    = blockIdx.y * TY;
  const int b     = blockIdx.z;

  const size_t plane = (size_t)HIN * WIN;
  const float* x0b = x0 + (size_t)b * CH * plane;
  const float* x1b = x1 + (size_t)b * CH * plane;

  f32x4_t acc[TY][2][5];
#pragma unroll
  for (int t = 0; t < TY; ++t)
#pragma unroll
    for (int mc = 0; mc < 2; ++mc)
#pragma unroll
      for (int T = 0; T < 5; ++T)
        acc[t][mc][T] = (f32x4_t){0.f, 0.f, 0.f, 0.f};

  float2 R0[12], R1[12];          // prefetched (ch even, ch odd) x-pairs

  // issue step-k global loads into registers (coalesced aligned float2)
  auto prefetch = [&](int k) {
    const int r = k >> 1, cc = k & 1;
    const int orow = y0 + r - 1;
    const bool rowok = (orow >= 0) && (orow < HIN);
    const int ro = rowok ? orow : 0;
    const float* s0p = x0b + (size_t)(cc * 32 + 2 * cpx) * plane + (size_t)ro * WIN;
    const float* s1p = x1b + (size_t)(cc * 32 + 2 * cpx) * plane + (size_t)ro * WIN;
#pragma unroll
    for (int it = 0; it < 5; ++it) {       // x0: wp 0..128
      const int wp = 32 * it + t5;
      const int xg = x0blk - 2 + 2 * wp;
      float2 a = {0.f, 0.f}, c = {0.f, 0.f};
      if (rowok && wp <= 128 && xg >= 0 && xg < WIN - 1) {
        a = *(const float2*)(s0p + xg);
        c = *(const float2*)(s0p + plane + xg);
      }
      R0[it] = a; R1[it] = c;
    }
#pragma unroll
    for (int it = 0; it < 7; ++it) {       // x1: wp 0..192
      const int wp = 32 * it + t5;
      const int xg = x0blk - 66 + 2 * wp;
      float2 a = {0.f, 0.f}, c = {0.f, 0.f};
      if (rowok && wp <= 192 && xg >= 0 && xg < WIN - 1) {
        a = *(const float2*)(s1p + xg);
        c = *(const float2*)(s1p + plane + xg);
      }
      R0[5 + it] = a; R1[5 + it] = c;
    }
  };

  // write prefetched registers to swizzled bf16 LDS buffer at byte base bb
  auto wstage = [&](int bb) {
#pragma unroll
    for (int it = 0; it < 12; ++it) {
      const bool isx1 = it >= 5;
      const int wp = 32 * (isx1 ? it - 5 : it) + t5;
      const int base = bb + (isx1 ? X1_OFF : X0_OFF);
      const int ps   = isx1 ? X1_PS : X0_PS;
      const int pmax = isx1 ? 192 : 128;
      unsigned pkA, pkB;
      asm("v_cvt_pk_bf16_f32 %0, %1, %2" : "=v"(pkA) : "v"(R0[it].x), "v"(R1[it].x));
      asm("v_cvt_pk_bf16_f32 %0, %1, %2" : "=v"(pkB) : "v"(R0[it].y), "v"(R1[it].y));
      if (wp >= 1 && wp <= pmax) {         // parity 1, pos wp-1
        const int pos = wp - 1;
        const int slot = (cpx >> 2) ^ ((pos >> 1) & 3);
        *(unsigned*)(smem + base + ps + pos * 64 + slot * 16 + (cpx & 3) * 4) = pkA;
      }
      if (wp <= pmax - 1) {                // parity 0, pos wp
        const int pos = wp;
        const int slot = (cpx >> 2) ^ ((pos >> 1) & 3);
        *(unsigned*)(smem + base + pos * 64 + slot * 16 + (cpx & 3) * 4) = pkB;
      }
    }
  };

  // prologue: stage step 0, launch step-1 loads
  prefetch(0);
  wstage(0);
  prefetch(1);
  asm volatile("s_waitcnt lgkmcnt(0)" ::: "memory");
  __builtin_amdgcn_s_barrier();
  asm volatile("" ::: "memory");

  // ============ K-loop: 4 padded rows x 2 channel chunks, 1 barrier/step ============
#pragma unroll
  for (int k = 0; k < NSTEP; ++k) {
    const int r = k >> 1;
    const int cur = (k & 1) * BUF_BYTES;

    bf16x8_t afr[2], bfr[6];
#pragma unroll
    for (int mc = 0; mc < 2; ++mc) {
      const int pos = 16 * (chunk0 + mc) + lm;
      const int slot = lk ^ ((pos >> 1) & 3);
      afr[mc] = *(const bf16x8_t*)(smem + cur + X0_OFF + p * X0_PS + pos * 64 + slot * 16);
    }
#pragma unroll
    for (int u = 0; u < 6; ++u) {
      const int pos = 16 * (chunk0 + u) + lm;
      const int slot = lk ^ ((pos >> 1) & 3);
      bfr[u] = *(const bf16x8_t*)(smem + cur + X1_OFF + p * X1_PS + pos * 64 + slot * 16);
    }
#pragma unroll
    for (int t = 0; t < TY; ++t) {
      if (t >= r - 2 && t <= r) {
#pragma unroll
        for (int mc = 0; mc < 2; ++mc)
#pragma unroll
          for (int T = 0; T < 5; ++T)
            acc[t][mc][T] = __builtin_amdgcn_mfma_f32_16x16x32_bf16(
                afr[mc], bfr[mc + T], acc[t][mc][T], 0, 0, 0);
      }
    }

    if (k < NSTEP - 1) {
      wstage(((k + 1) & 1) * BUF_BYTES);   // consumes R (vmcnt waits), other buffer
      if (k + 2 < NSTEP) prefetch(k + 2);  // next loads fly over next step
      asm volatile("s_waitcnt lgkmcnt(0)" ::: "memory");
      __builtin_amdgcn_s_barrier();
      asm volatile("" ::: "memory");
    }
  }

  // ============ epilogue: full-Q dump per row (aliases staging), rcp-normalize ============
  float* Q   = (float*)(smem + QB_OFF);
  float* s0x = (float*)(smem + S0X_OFF);
  float* l0x = (float*)(smem + L0X_OFF);
  float* s1x = (float*)(smem + S1X_OFF);
  float* l1x = (float*)(smem + L1X_OFF);
  const float invn = 1.f / 576.f;

#pragma unroll
  for (int t = 0; t < TY; ++t) {
    const int row = y0 + t;
    __syncthreads();                       // staging (t=0) / previous row's Q (t=1) readers done
    for (int i = tid; i < 254; i += 512) {
      const int x = x0blk + i;
      const size_t o = ((size_t)b * HIN + row) * WIN + x;
      s0x[i] = (x < WIN) ? ws[SB0_OFF + o] : 0.f;
      l0x[i] = (x < WIN) ? ws[LB0_OFF + o] : 0.f;
    }
    for (int j2 = tid; j2 < 382; j2 += 512) {
      const int idx = x0blk + 2 + j2;
      const size_t o = ((size_t)b * HIN + row) * 648 + idx;
      s1x[j2] = (idx < 648) ? ws[SB1_OFF + o] : 0.f;
      l1x[j2] = (idx < 648) ? ws[LB1_OFF + o] : 0.f;
    }
    // single unpredicated-band dump of all 65 diagonals
#pragma unroll
    for (int mc = 0; mc < 2; ++mc)
#pragma unroll
      for (int T = 0; T < 5; ++T)
#pragma unroll
        for (int q = 0; q < 4; ++q) {
          const int mg = 16 * (chunk0 + mc) + lk * 4 + q;
          const int di = 16 * T + lm - 4 * lk - q;
          if (di >= 0 && di <= 64)
            Q[di * 257 + 2 * mg + p] = acc[t][mc][T][q];
        }
    __syncthreads();
    for (int oi = tid; oi < NDISP * TX; oi += 512) {
      const int di = oi / TX;
      const int xl = oi - di * TX;
      const int x = x0blk + xl;
      if (x < WIN) {
        const float q3 = Q[di * 257 + xl] + Q[di * 257 + xl + 1] + Q[di * 257 + xl + 2];
        const int j = xl + 2 * di;
        const float numer = q3 - s0x[xl] * s1x[j] * invn;
        const float den = l0x[xl] * l1x[j] + 1e-8f;
        float rd;
        asm("v_rcp_f32 %0, %1" : "=v"(rd) : "v"(den));
        out[(((size_t)b * NDISP + di) * HIN + row) * WIN + x] = numer * rd;
      }
    }
  }
}

extern "C" void kernel_launch(void* const* d_in, const int* in_sizes, int n_in,
                              void* d_out, int out_size, void* d_ws, size_t ws_size,
                              hipStream_t stream) {
  const float* x0 = (const float*)d_in[0];
  const float* x1 = (const float*)d_in[1];
  float* out = (float*)d_out;
  float* wsf = (float*)d_ws;

  colsum_kernel<<<dim3(HIN, BATCH), 512, 0, stream>>>(x0, x1, wsf);
  boxnorm_kernel<<<dim3(HIN, BATCH), 512, 0, stream>>>(wsf);
  corrzn_kernel<<<dim3(3, HIN / TY, BATCH), 512, 0, stream>>>(x0, x1, wsf, out);
}